// Round 1
// baseline (1804.472 us; speedup 1.0000x reference)
//
#include <hip/hip_runtime.h>
#include <math.h>

#define BB 4
#define NN 2048
#define IN_DIM 256
#define HH 8
#define DD 64
#define HD 512
#define NEG_SLOPE 0.2f

// ---------------- K1: mapped = nodes @ proj_weights  (8192x256 @ 256x512) ----
__global__ __launch_bounds__(256) void proj_gemm(const float* __restrict__ A,
                                                 const float* __restrict__ W,
                                                 float* __restrict__ C) {
  __shared__ float As[32][68];  // [k][row], padded
  __shared__ float Ws[32][68];  // [k][col], padded
  const int t = threadIdx.x;
  const int tx = t & 15, ty = t >> 4;
  const int i0 = blockIdx.x * 64;
  const int c0 = blockIdx.y * 64;
  float acc[4][4] = {};
  for (int k0 = 0; k0 < IN_DIM; k0 += 32) {
    __syncthreads();
#pragma unroll
    for (int q = 0; q < 8; ++q) {
      int idx = t + q * 256;
      int k = idx & 31, r = idx >> 5;
      As[k][r] = A[(i0 + r) * IN_DIM + k0 + k];
    }
#pragma unroll
    for (int q = 0; q < 8; ++q) {
      int idx = t + q * 256;
      int c = idx & 63, kk = idx >> 6;
      Ws[kk][c] = W[(k0 + kk) * HD + c0 + c];
    }
    __syncthreads();
#pragma unroll
    for (int kk = 0; kk < 32; ++kk) {
      float4 a = *(const float4*)&As[kk][ty * 4];
      float4 bv = *(const float4*)&Ws[kk][tx * 4];
      float av[4] = {a.x, a.y, a.z, a.w};
      float bb[4] = {bv.x, bv.y, bv.z, bv.w};
#pragma unroll
      for (int m = 0; m < 4; ++m)
#pragma unroll
        for (int n = 0; n < 4; ++n) acc[m][n] += av[m] * bb[n];
    }
  }
#pragma unroll
  for (int m = 0; m < 4; ++m) {
    float4 v = make_float4(acc[m][0], acc[m][1], acc[m][2], acc[m][3]);
    *(float4*)&C[(size_t)(i0 + ty * 4 + m) * HD + c0 + tx * 4] = v;
  }
}

// ---------------- K2: el/er = <mapped row, a_l/a_r> ------------------------
__global__ __launch_bounds__(256) void el_er_kernel(const float* __restrict__ mapped,
                                                    const float* __restrict__ aw,
                                                    float* __restrict__ el,
                                                    float* __restrict__ er) {
  int wid = blockIdx.x * 4 + (threadIdx.x >> 6);  // global wave id = bh*N + n
  int l = threadIdx.x & 63;
  int n = wid & (NN - 1);
  int bh = wid >> 11;
  int b = bh >> 3, h = bh & 7;
  float v = mapped[((size_t)(b * NN + n) * HD) + h * DD + l];
  float pl = v * aw[h * 2 * DD + l];
  float pr = v * aw[h * 2 * DD + DD + l];
#pragma unroll
  for (int s = 32; s > 0; s >>= 1) {
    pl += __shfl_xor(pl, s);
    pr += __shfl_xor(pr, s);
  }
  if (l == 0) {
    el[wid] = pl;
    er[wid] = pr;
  }
}

// ---------------- K3: er_max per (b,h) -------------------------------------
__global__ __launch_bounds__(256) void ermax_kernel(const float* __restrict__ er,
                                                    float* __restrict__ er_max) {
  int bh = blockIdx.x;
  int t = threadIdx.x;
  float m = -1e30f;
  for (int idx = t; idx < NN; idx += 256) m = fmaxf(m, er[bh * NN + idx]);
  __shared__ float red[256];
  red[t] = m;
  __syncthreads();
  for (int s = 128; s > 0; s >>= 1) {
    if (t < s) red[t] = fmaxf(red[t], red[t + s]);
    __syncthreads();
  }
  if (t == 0) er_max[bh] = red[0];
}

// ---------------- K4: fused masked-softmax attention + sigmoid -------------
__global__ __launch_bounds__(256) void gat_attn(const float* __restrict__ mapped,
                                                const int* __restrict__ edges,
                                                const float* __restrict__ el,
                                                const float* __restrict__ er,
                                                const float* __restrict__ er_max,
                                                float* __restrict__ out) {
  __shared__ float mapped_s[64][68];  // [j][d]
  __shared__ float p_s[64][68];       // [i][j]
  __shared__ float er_t[64];
  __shared__ float el_s[64];
  __shared__ float m_s[64];
  const int t = threadIdx.x;
  const int w = t >> 6, l = t & 63;
  const int i0 = blockIdx.x * 64;
  const int h = blockIdx.y, b = blockIdx.z;
  const int bh = b * HH + h;
  const float ermax = er_max[bh];
  if (t < 64) {
    float e = el[bh * NN + i0 + t];
    el_s[t] = e;
    float s0 = e + ermax;
    m_s[t] = s0 > 0.f ? s0 : NEG_SLOPE * s0;  // upper bound of row max
  }
  float acc[16];
  float Lp[16];
#pragma unroll
  for (int s = 0; s < 16; ++s) {
    acc[s] = 0.f;
    Lp[s] = 0.f;
  }

  for (int j0 = 0; j0 < NN; j0 += 64) {
    __syncthreads();  // protect mapped_s/p_s from previous iteration readers
#pragma unroll
    for (int q = 0; q < 16; ++q) {
      int jr = w + 4 * q;
      mapped_s[jr][l] = mapped[((size_t)(b * NN + j0 + jr) * HD) + h * DD + l];
    }
    if (t < 64) er_t[t] = er[bh * NN + j0 + t];
    __syncthreads();
    // score phase: wave w lane l handles (row = w+4s, j = l)
#pragma unroll
    for (int s = 0; s < 16; ++s) {
      int ri = w + 4 * s;
      int i = i0 + ri;
      int e = edges[(size_t)(b * NN + i) * NN + j0 + l];
      float sc = el_s[ri] + er_t[l];
      sc = sc > 0.f ? sc : NEG_SLOPE * sc;
      float p = (e != 0) ? __expf(sc - m_s[ri]) : 0.f;
      p_s[ri][l] = p;
      Lp[s] += p;
    }
    __syncthreads();
    // PV phase: wave w lane l = d, rows w+4s
#pragma unroll
    for (int j = 0; j < 64; ++j) {
      float v = mapped_s[j][l];
#pragma unroll
      for (int s = 0; s < 16; ++s) {
        acc[s] += p_s[w + 4 * s][j] * v;
      }
    }
  }
  // epilogue: normalize + sigmoid
#pragma unroll
  for (int s = 0; s < 16; ++s) {
    float L = Lp[s];
#pragma unroll
    for (int sh = 32; sh > 0; sh >>= 1) L += __shfl_xor(L, sh);
    float o = acc[s] / L;
    float sig = 1.f / (1.f + __expf(-o));
    out[((size_t)(b * NN + i0 + w + 4 * s) * HD) + h * DD + l] = sig;
  }
}

extern "C" void kernel_launch(void* const* d_in, const int* in_sizes, int n_in,
                              void* d_out, int out_size, void* d_ws, size_t ws_size,
                              hipStream_t stream) {
  const float* nodes = (const float*)d_in[0];
  const int* edges = (const int*)d_in[1];
  const float* pw = (const float*)d_in[2];
  const float* aw = (const float*)d_in[3];
  float* out = (float*)d_out;

  float* mapped = (float*)d_ws;                       // B*N*HD floats (16.8 MB)
  float* el = mapped + (size_t)BB * NN * HD;          // B*H*N
  float* er = el + (size_t)BB * HH * NN;              // B*H*N
  float* ermax = er + (size_t)BB * HH * NN;           // B*H

  proj_gemm<<<dim3(NN * BB / 64, HD / 64), 256, 0, stream>>>(nodes, pw, mapped);
  el_er_kernel<<<dim3(BB * HH * NN / 4), 256, 0, stream>>>(mapped, aw, el, er);
  ermax_kernel<<<dim3(BB * HH), 256, 0, stream>>>(er, ermax);
  gat_attn<<<dim3(NN / 64, HH, BB), 256, 0, stream>>>(mapped, edges, el, er, ermax, out);
}

// Round 2
// 131.591 us; speedup vs baseline: 13.7128x; 13.7128x over previous
//
#include <hip/hip_runtime.h>
#include <hip/hip_fp16.h>
#include <math.h>

#define NEG 0.2f

typedef float f32x4 __attribute__((ext_vector_type(4)));
typedef _Float16 half8 __attribute__((ext_vector_type(8)));

// ---------------- K1: fused projection GEMM + el/er + f16 transpose --------
// C-tile (64 rows x 64 cols) of mapped, cols = head h exactly.
// Outputs: mapped_t[bh][d][n] (f16), el[bh][n], er[bh][n]. No f32 mapped.
__global__ __launch_bounds__(256) void proj_fused(const float* __restrict__ A,
                                                  const float* __restrict__ W,
                                                  const float* __restrict__ aw,
                                                  ushort* __restrict__ mt,
                                                  float* __restrict__ el,
                                                  float* __restrict__ er) {
  __shared__ float As[32][68];
  __shared__ float Ws[32][68];
  __shared__ ushort ct[64][72];  // transposed f16 tile [d][n_local]
  const int t = threadIdx.x;
  const int tx = t & 15, ty = t >> 4;
  const int i0 = blockIdx.x * 64;  // flattened row over B*N
  const int h = blockIdx.y;
  const int c0 = h * 64;
  const int b = i0 >> 11;
  const int n0 = i0 & 2047;
  const int bh = b * 8 + h;
  float acc[4][4] = {};
  for (int k0 = 0; k0 < 256; k0 += 32) {
    __syncthreads();
#pragma unroll
    for (int q = 0; q < 8; ++q) {
      int idx = t + q * 256;
      int k = idx & 31, r = idx >> 5;
      As[k][r] = A[(size_t)(i0 + r) * 256 + k0 + k];
    }
#pragma unroll
    for (int q = 0; q < 8; ++q) {
      int idx = t + q * 256;
      int c = idx & 63, kk = idx >> 6;
      Ws[kk][c] = W[(size_t)(k0 + kk) * 512 + c0 + c];
    }
    __syncthreads();
#pragma unroll
    for (int kk = 0; kk < 32; ++kk) {
      float4 a = *(const float4*)&As[kk][ty * 4];
      float4 bv = *(const float4*)&Ws[kk][tx * 4];
      float av[4] = {a.x, a.y, a.z, a.w};
      float bb[4] = {bv.x, bv.y, bv.z, bv.w};
#pragma unroll
      for (int m = 0; m < 4; ++m)
#pragma unroll
        for (int n = 0; n < 4; ++n) acc[m][n] += av[m] * bb[n];
    }
  }
  // ---- el/er: dot of each row's 64-wide head slice with a_l/a_r ----
  float4 al = *(const float4*)&aw[h * 128 + tx * 4];
  float4 ar = *(const float4*)&aw[h * 128 + 64 + tx * 4];
#pragma unroll
  for (int m = 0; m < 4; ++m) {
    float pl = acc[m][0] * al.x + acc[m][1] * al.y + acc[m][2] * al.z + acc[m][3] * al.w;
    float pr = acc[m][0] * ar.x + acc[m][1] * ar.y + acc[m][2] * ar.z + acc[m][3] * ar.w;
#pragma unroll
    for (int s = 1; s < 16; s <<= 1) {
      pl += __shfl_xor(pl, s);
      pr += __shfl_xor(pr, s);
    }
    if (tx == 0) {
      el[bh * 2048 + n0 + ty * 4 + m] = pl;
      er[bh * 2048 + n0 + ty * 4 + m] = pr;
    }
  }
  // ---- transposed f16 tile: ct[d=tx*4+n][j=ty*4+m] ----
#pragma unroll
  for (int n = 0; n < 4; ++n) {
    ushort4 us;
    us.x = __half_as_ushort(__float2half(acc[0][n]));
    us.y = __half_as_ushort(__float2half(acc[1][n]));
    us.z = __half_as_ushort(__float2half(acc[2][n]));
    us.w = __half_as_ushort(__float2half(acc[3][n]));
    *(ushort4*)&ct[tx * 4 + n][ty * 4] = us;
  }
  __syncthreads();
#pragma unroll
  for (int q = 0; q < 2; ++q) {
    int ch = t + q * 256;
    int d = ch >> 3, cg = ch & 7;
    int4 v = *(const int4*)&ct[d][cg * 8];
    *(int4*)&mt[((size_t)bh * 64 + d) * 2048 + n0 + cg * 8] = v;
  }
}

// ---------------- K3: er_max per (b,h) -------------------------------------
__global__ __launch_bounds__(256) void ermax_kernel(const float* __restrict__ er,
                                                    float* __restrict__ er_max) {
  int bh = blockIdx.x;
  int t = threadIdx.x;
  float m = -1e30f;
  for (int idx = t; idx < 2048; idx += 256) m = fmaxf(m, er[bh * 2048 + idx]);
  __shared__ float red[256];
  red[t] = m;
  __syncthreads();
  for (int s = 128; s > 0; s >>= 1) {
    if (t < s) red[t] = fmaxf(red[t], red[t + s]);
    __syncthreads();
  }
  if (t == 0) er_max[bh] = red[0];
}

// ---------------- K4: fused masked softmax + PV via MFMA -------------------
__global__ __launch_bounds__(256) void gat_attn(const ushort* __restrict__ mt,
                                                const int* __restrict__ edges,
                                                const float* __restrict__ el,
                                                const float* __restrict__ er,
                                                const float* __restrict__ ermax,
                                                float* __restrict__ out) {
  __shared__ ushort vt[64][72];  // V^T tile [d][j], f16
  __shared__ float er_s[2048];
  const int t = threadIdx.x;
  const int w = t >> 6, l = t & 63;
  const int r16 = l & 15, hi = l >> 4;
  const int i0 = blockIdx.x * 64;
  const int h = blockIdx.y, b = blockIdx.z;
  const int bh = b * 8 + h;
#pragma unroll
  for (int q = 0; q < 2; ++q) {
    int idx = t * 4 + q * 1024;
    *(float4*)&er_s[idx] = *(const float4*)&er[bh * 2048 + idx];
  }
  const int irow = i0 + w * 16 + r16;  // this lane's score row
  const float el_r = el[bh * 2048 + irow];
  const float emx = ermax[bh];
  const float s0 = el_r + emx;
  const float m_r = s0 > 0.f ? s0 : NEG * s0;  // upper bound of row max
  const size_t erowb = (size_t)(b * 2048 + irow) * 2048;
  f32x4 acc[4];
#pragma unroll
  for (int nt = 0; nt < 4; ++nt) acc[nt] = (f32x4){0.f, 0.f, 0.f, 0.f};
  float Lp = 0.f;

  for (int j0 = 0; j0 < 2048; j0 += 64) {
    __syncthreads();  // prev MFMA done with vt; er_s ready on first iter
    // stage V^T tile (coalesced global f16 -> LDS b128)
#pragma unroll
    for (int q = 0; q < 2; ++q) {
      int ch = t + q * 256;
      int d = ch >> 3, cg = ch & 7;
      int4 v = *(const int4*)&mt[((size_t)bh * 64 + d) * 2048 + j0 + cg * 8];
      *(int4*)&vt[d][cg * 8] = v;
    }
    // score phase: P built directly in A-fragment registers
    half8 af[2];
#pragma unroll
    for (int g = 0; g < 2; ++g) {
      int jb = g * 32 + hi * 8;
      const int* ep = edges + erowb + j0 + jb;
      int4 e0 = *(const int4*)ep;
      int4 e1 = *(const int4*)(ep + 4);
      float4 u0 = *(const float4*)&er_s[j0 + jb];
      float4 u1 = *(const float4*)&er_s[j0 + jb + 4];
      int ev[8] = {e0.x, e0.y, e0.z, e0.w, e1.x, e1.y, e1.z, e1.w};
      float uv[8] = {u0.x, u0.y, u0.z, u0.w, u1.x, u1.y, u1.z, u1.w};
      union {
        ushort us[8];
        half8 v;
      } fr;
#pragma unroll
      for (int c = 0; c < 8; ++c) {
        float sc = el_r + uv[c];
        sc = sc > 0.f ? sc : NEG * sc;
        float p = ev[c] ? __expf(sc - m_r) : 0.f;
        __half hp = __float2half(p);
        fr.us[c] = __half_as_ushort(hp);
        Lp += __half2float(hp);  // denominator consistent with rounded P
      }
      af[g] = fr.v;
    }
    __syncthreads();  // vt ready
#pragma unroll
    for (int g = 0; g < 2; ++g)
#pragma unroll
      for (int nt = 0; nt < 4; ++nt) {
        half8 bfr = *(const half8*)&vt[nt * 16 + r16][g * 32 + hi * 8];
        acc[nt] = __builtin_amdgcn_mfma_f32_16x16x32_f16(af[g], bfr, acc[nt], 0, 0, 0);
      }
  }
  // row-sum L: this lane's partial covers j-chunks of row r16; reduce over hi
  Lp += __shfl_xor(Lp, 16);
  Lp += __shfl_xor(Lp, 32);
  // epilogue: D row = hi*4+reg, col = nt*16 + r16
#pragma unroll
  for (int reg = 0; reg < 4; ++reg) {
    float Lrow = __shfl(Lp, hi * 4 + reg);
    int orow = i0 + w * 16 + hi * 4 + reg;
#pragma unroll
    for (int nt = 0; nt < 4; ++nt) {
      float o = acc[nt][reg] / Lrow;
      float sig = 1.f / (1.f + __expf(-o));
      out[(size_t)(b * 2048 + orow) * 512 + h * 64 + nt * 16 + r16] = sig;
    }
  }
}

extern "C" void kernel_launch(void* const* d_in, const int* in_sizes, int n_in,
                              void* d_out, int out_size, void* d_ws, size_t ws_size,
                              hipStream_t stream) {
  const float* nodes = (const float*)d_in[0];
  const int* edges = (const int*)d_in[1];
  const float* pw = (const float*)d_in[2];
  const float* aw = (const float*)d_in[3];
  float* out = (float*)d_out;

  ushort* mt = (ushort*)d_ws;                          // 4*8*64*2048 f16 = 8.39 MB
  float* el = (float*)((char*)d_ws + 8388608);         // 65536 f32
  float* er = el + 65536;                              // 65536 f32
  float* ermax = er + 65536;                           // 32 f32

  proj_fused<<<dim3(128, 8), 256, 0, stream>>>(nodes, pw, aw, mt, el, er);
  ermax_kernel<<<32, 256, 0, stream>>>(er, ermax);
  gat_attn<<<dim3(32, 8, 4), 256, 0, stream>>>(mt, edges, el, er, ermax, out);
}

// Round 4
// 111.819 us; speedup vs baseline: 16.1374x; 1.1768x over previous
//
#include <hip/hip_runtime.h>
#include <hip/hip_fp16.h>
#include <math.h>

#define NEG 0.2f
#define LOG2E 1.4426950408889634f

typedef float f32x4 __attribute__((ext_vector_type(4)));
typedef _Float16 half8 __attribute__((ext_vector_type(8)));
typedef _Float16 half2v __attribute__((ext_vector_type(2)));

#if __has_builtin(__builtin_amdgcn_exp2f)
#define EXP2F(x) __builtin_amdgcn_exp2f(x)
#else
#define EXP2F(x) exp2f(x)
#endif

__device__ inline half2v pack2(float a, float b) {
#if __has_builtin(__builtin_amdgcn_cvt_pkrtz)
  union {
    __fp16 fp[2];
    half2v h;
  } u;
  *(decltype(__builtin_amdgcn_cvt_pkrtz(a, b))*)u.fp = __builtin_amdgcn_cvt_pkrtz(a, b);
  return u.h;
#else
  half2v r;
  r[0] = (_Float16)a;
  r[1] = (_Float16)b;
  return r;
#endif
}

// ---------------- K0: pack edges (0/1 int32) into bitmask via ballot -------
__global__ __launch_bounds__(256) void pack_edges(const int* __restrict__ e,
                                                  uint* __restrict__ epk) {
  const int nw = gridDim.x * 4;
  int wid = blockIdx.x * 4 + (threadIdx.x >> 6);
  const int l = threadIdx.x & 63;
  for (; wid < 262144; wid += nw) {  // 4*2048*2048/64 chunks
    int v = e[(size_t)wid * 64 + l];
    unsigned long long m = __ballot(v != 0);
    if (l == 0) *(unsigned long long*)(epk + (size_t)wid * 2) = m;
  }
}

// ---------------- K1: fused projection GEMM + el/er + f16 transpose --------
__global__ __launch_bounds__(256) void proj_fused(const float* __restrict__ A,
                                                  const float* __restrict__ W,
                                                  const float* __restrict__ aw,
                                                  ushort* __restrict__ mt,
                                                  float* __restrict__ el,
                                                  float* __restrict__ er) {
  __shared__ float As[32][68];
  __shared__ float Ws[32][68];
  __shared__ ushort ct[64][72];
  const int t = threadIdx.x;
  const int tx = t & 15, ty = t >> 4;
  const int i0 = blockIdx.x * 64;
  const int h = blockIdx.y;
  const int c0 = h * 64;
  const int b = i0 >> 11;
  const int n0 = i0 & 2047;
  const int bh = b * 8 + h;
  float acc[4][4] = {};
  for (int k0 = 0; k0 < 256; k0 += 32) {
    __syncthreads();
#pragma unroll
    for (int q = 0; q < 8; ++q) {
      int idx = t + q * 256;
      int k = idx & 31, r = idx >> 5;
      As[k][r] = A[(size_t)(i0 + r) * 256 + k0 + k];
    }
#pragma unroll
    for (int q = 0; q < 8; ++q) {
      int idx = t + q * 256;
      int c = idx & 63, kk = idx >> 6;
      Ws[kk][c] = W[(size_t)(k0 + kk) * 512 + c0 + c];
    }
    __syncthreads();
#pragma unroll
    for (int kk = 0; kk < 32; ++kk) {
      float4 a = *(const float4*)&As[kk][ty * 4];
      float4 bv = *(const float4*)&Ws[kk][tx * 4];
      float av[4] = {a.x, a.y, a.z, a.w};
      float bb[4] = {bv.x, bv.y, bv.z, bv.w};
#pragma unroll
      for (int m = 0; m < 4; ++m)
#pragma unroll
        for (int n = 0; n < 4; ++n) acc[m][n] += av[m] * bb[n];
    }
  }
  float4 al = *(const float4*)&aw[h * 128 + tx * 4];
  float4 ar = *(const float4*)&aw[h * 128 + 64 + tx * 4];
#pragma unroll
  for (int m = 0; m < 4; ++m) {
    float pl = acc[m][0] * al.x + acc[m][1] * al.y + acc[m][2] * al.z + acc[m][3] * al.w;
    float pr = acc[m][0] * ar.x + acc[m][1] * ar.y + acc[m][2] * ar.z + acc[m][3] * ar.w;
#pragma unroll
    for (int s = 1; s < 16; s <<= 1) {
      pl += __shfl_xor(pl, s);
      pr += __shfl_xor(pr, s);
    }
    if (tx == 0) {
      el[bh * 2048 + n0 + ty * 4 + m] = pl;
      er[bh * 2048 + n0 + ty * 4 + m] = pr;
    }
  }
#pragma unroll
  for (int n = 0; n < 4; ++n) {
    ushort4 us;
    us.x = __half_as_ushort(__float2half(acc[0][n]));
    us.y = __half_as_ushort(__float2half(acc[1][n]));
    us.z = __half_as_ushort(__float2half(acc[2][n]));
    us.w = __half_as_ushort(__float2half(acc[3][n]));
    *(ushort4*)&ct[tx * 4 + n][ty * 4] = us;
  }
  __syncthreads();
#pragma unroll
  for (int q = 0; q < 2; ++q) {
    int ch = t + q * 256;
    int d = ch >> 3, cg = ch & 7;
    int4 v = *(const int4*)&ct[d][cg * 8];
    *(int4*)&mt[((size_t)bh * 64 + d) * 2048 + n0 + cg * 8] = v;
  }
}

// ---------------- K2: er_max per (b,h) -------------------------------------
__global__ __launch_bounds__(256) void ermax_kernel(const float* __restrict__ er,
                                                    float* __restrict__ er_max) {
  int bh = blockIdx.x;
  int t = threadIdx.x;
  float m = -1e30f;
  for (int idx = t; idx < 2048; idx += 256) m = fmaxf(m, er[bh * 2048 + idx]);
  __shared__ float red[256];
  red[t] = m;
  __syncthreads();
  for (int s = 128; s > 0; s >>= 1) {
    if (t < s) red[t] = fmaxf(red[t], red[t + s]);
    __syncthreads();
  }
  if (t == 0) er_max[bh] = red[0];
}

// ---------------- K3: fused masked softmax + PV via MFMA, 2-way j-split ----
__global__ __launch_bounds__(512, 8) void gat_attn(const ushort* __restrict__ mt,
                                                   const uint* __restrict__ epk,
                                                   const float* __restrict__ el,
                                                   const float* __restrict__ er,
                                                   const float* __restrict__ ermax,
                                                   float* __restrict__ out) {
  __shared__ __align__(16) char smem[26624];
  ushort(*vt)[64][72] = (ushort(*)[64][72])smem;  // [half][d][j], f16
  float* er_s = (float*)(smem + 18432);           // 2048 floats
  const int t = threadIdx.x;
  const int l = t & 63;
  const int half = t >> 8;
  const int th = t & 255;
  const int wq = (t >> 6) & 3;
  const int r16 = l & 15, hi = l >> 4;
  const int sh8 = hi * 8;
  const int i0 = blockIdx.x * 64;
  const int h = blockIdx.y, b = blockIdx.z;
  const int bh = b * 8 + h;
  *(float4*)&er_s[t * 4] = *(const float4*)&er[(size_t)bh * 2048 + t * 4];
  const int irow = i0 + wq * 16 + r16;
  const float el_r = el[(size_t)bh * 2048 + irow];
  const float emx = ermax[bh];
  const float s0 = el_r + emx;
  const float m_r = fmaxf(s0, NEG * s0);  // upper bound of row max score
  const float m2 = m_r * LOG2E;
  const uint* erow = epk + (size_t)(b * 2048 + irow) * 64;
  f32x4 acc[4];
  f32x4 accL = {0.f, 0.f, 0.f, 0.f};
#pragma unroll
  for (int nt = 0; nt < 4; ++nt) acc[nt] = (f32x4){0.f, 0.f, 0.f, 0.f};
  half8 ones;
#pragma unroll
  for (int c = 0; c < 8; ++c) ones[c] = (_Float16)1.f;

  const int jbase = half * 1024;
  const size_t mtb = (size_t)bh * 64;
  for (int jt = 0; jt < 16; ++jt) {
    const int j0 = jbase + jt * 64;
    const unsigned long long wpair = *(const unsigned long long*)(erow + (j0 >> 5));
    const uint wsh0 = ((uint)wpair) >> sh8;
    const uint wsh1 = ((uint)(wpair >> 32)) >> sh8;
    __syncthreads();  // previous tile's MFMA done with vt
#pragma unroll
    for (int q = 0; q < 2; ++q) {
      int ch = th + q * 256;
      int d = ch >> 3, cg = ch & 7;
      int4 v = *(const int4*)&mt[(mtb + d) * 2048 + j0 + cg * 8];
      *(int4*)&vt[half][d][cg * 8] = v;
    }
    half8 af[2];
#pragma unroll
    for (int g = 0; g < 2; ++g) {
      float4 u0 = *(const float4*)&er_s[j0 + g * 32 + sh8];
      float4 u1 = *(const float4*)&er_s[j0 + g * 32 + sh8 + 4];
      float uv[8] = {u0.x, u0.y, u0.z, u0.w, u1.x, u1.y, u1.z, u1.w};
      const uint wg = g ? wsh1 : wsh0;
      float pv[8];
#pragma unroll
      for (int c = 0; c < 8; ++c) {
        float s = el_r + uv[c];
        s = fmaxf(s, NEG * s);                       // leaky_relu
        float tt = __builtin_fmaf(s, LOG2E, -m2);    // (s - m_r) * log2e, <= 0
        float p = EXP2F(tt);
        uint bit = (wg >> c) & 1;
        pv[c] = p * (float)bit;                      // mask (no inf: tt <= 0)
      }
      union {
        half2v h2[4];
        half8 v8;
      } fr;
#pragma unroll
      for (int c = 0; c < 4; ++c) fr.h2[c] = pack2(pv[2 * c], pv[2 * c + 1]);
      af[g] = fr.v8;
    }
    __syncthreads();  // vt ready
#pragma unroll
    for (int g = 0; g < 2; ++g) {
      accL = __builtin_amdgcn_mfma_f32_16x16x32_f16(af[g], ones, accL, 0, 0, 0);
#pragma unroll
      for (int nt = 0; nt < 4; ++nt) {
        half8 bfr = *(const half8*)&vt[half][nt * 16 + r16][g * 32 + sh8];
        acc[nt] = __builtin_amdgcn_mfma_f32_16x16x32_f16(af[g], bfr, acc[nt], 0, 0, 0);
      }
    }
  }
  // ---- combine j-halves via LDS, then epilogue on half 0 ----
  __syncthreads();
  float* red = (float*)smem;  // 256 lanes * 21 floats = 21504 B
  if (half == 1) {
    float* dst = red + th * 21;
#pragma unroll
    for (int nt = 0; nt < 4; ++nt)
#pragma unroll
      for (int k = 0; k < 4; ++k) dst[nt * 4 + k] = acc[nt][k];
#pragma unroll
    for (int k = 0; k < 4; ++k) dst[16 + k] = accL[k];
  }
  __syncthreads();
  if (half == 0) {
    const float* src = red + th * 21;
#pragma unroll
    for (int reg = 0; reg < 4; ++reg) {
      float Lrow = accL[reg] + src[16 + reg];
      float invL = 1.f / Lrow;
      int orow = i0 + wq * 16 + hi * 4 + reg;
#pragma unroll
      for (int nt = 0; nt < 4; ++nt) {
        float o = (acc[nt][reg] + src[nt * 4 + reg]) * invL;
        float sig = 1.f / (1.f + __expf(-o));
        out[(size_t)(b * 2048 + orow) * 512 + h * 64 + nt * 16 + r16] = sig;
      }
    }
  }
}

extern "C" void kernel_launch(void* const* d_in, const int* in_sizes, int n_in,
                              void* d_out, int out_size, void* d_ws, size_t ws_size,
                              hipStream_t stream) {
  const float* nodes = (const float*)d_in[0];
  const int* edges = (const int*)d_in[1];
  const float* pw = (const float*)d_in[2];
  const float* aw = (const float*)d_in[3];
  float* out = (float*)d_out;

  ushort* mt = (ushort*)d_ws;                         // 8,388,608 B
  float* el = (float*)((char*)d_ws + 8388608);        // 262,144 B
  float* er = (float*)((char*)d_ws + 8650752);        // 262,144 B
  float* ermax = (float*)((char*)d_ws + 8912896);     // 128 B
  uint* epk = (uint*)((char*)d_ws + 8913024);         // 2,097,152 B

  pack_edges<<<2048, 256, 0, stream>>>(edges, epk);
  proj_fused<<<dim3(128, 8), 256, 0, stream>>>(nodes, pw, aw, mt, el, er);
  ermax_kernel<<<32, 256, 0, stream>>>(er, ermax);
  gat_attn<<<dim3(32, 8, 4), 512, 0, stream>>>(mt, epk, el, er, ermax, out);
}

// Round 5
// 107.644 us; speedup vs baseline: 16.7633x; 1.0388x over previous
//
#include <hip/hip_runtime.h>
#include <hip/hip_fp16.h>
#include <math.h>

#define NEG 0.2f
#define LOG2E 1.4426950408889634f

typedef float f32x4 __attribute__((ext_vector_type(4)));
typedef _Float16 half8 __attribute__((ext_vector_type(8)));
typedef _Float16 half2v __attribute__((ext_vector_type(2)));

#if __has_builtin(__builtin_amdgcn_exp2f)
#define EXP2F(x) __builtin_amdgcn_exp2f(x)
#else
#define EXP2F(x) exp2f(x)
#endif

__device__ inline half2v pack2(float a, float b) {
#if __has_builtin(__builtin_amdgcn_cvt_pkrtz)
  union {
    __fp16 fp[2];
    half2v h;
  } u;
  *(decltype(__builtin_amdgcn_cvt_pkrtz(a, b))*)u.fp = __builtin_amdgcn_cvt_pkrtz(a, b);
  return u.h;
#else
  half2v r;
  r[0] = (_Float16)a;
  r[1] = (_Float16)b;
  return r;
#endif
}

// ---------------- K0: pack edges (0/1 int32) into bitmask via ballot -------
__global__ __launch_bounds__(256) void pack_edges(const int* __restrict__ e,
                                                  uint* __restrict__ epk) {
  const int nw = gridDim.x * 4;
  int wid = blockIdx.x * 4 + (threadIdx.x >> 6);
  const int l = threadIdx.x & 63;
  for (; wid < 262144; wid += nw) {
    int v = e[(size_t)wid * 64 + l];
    unsigned long long m = __ballot(v != 0);
    if (l == 0) *(unsigned long long*)(epk + (size_t)wid * 2) = m;
  }
}

// ---------------- K1: fused projection GEMM + el/er + fragment-order mt ----
// mt layout: per (bh, jt in 0..31): 8 fragments f=g*4+nt, each 64 lanes x 8 f16:
//   mt[((bh*32+jt)*4096) + f*512 + l*8 + c] = V^T[d = nt*16+(l&15)][j = g*32+(l>>4)*8+c]
__global__ __launch_bounds__(256) void proj_fused(const float* __restrict__ A,
                                                  const float* __restrict__ W,
                                                  const float* __restrict__ aw,
                                                  ushort* __restrict__ mt,
                                                  float* __restrict__ el,
                                                  float* __restrict__ er) {
  __shared__ float As[32][68];
  __shared__ float Ws[32][68];
  __shared__ ushort ct[64][72];  // [d][j_local]
  const int t = threadIdx.x;
  const int tx = t & 15, ty = t >> 4;
  const int i0 = blockIdx.x * 64;
  const int h = blockIdx.y;
  const int c0 = h * 64;
  const int b = i0 >> 11;
  const int n0 = i0 & 2047;
  const int bh = b * 8 + h;
  float acc[4][4] = {};
  for (int k0 = 0; k0 < 256; k0 += 32) {
    __syncthreads();
#pragma unroll
    for (int q = 0; q < 8; ++q) {
      int idx = t + q * 256;
      int k = idx & 31, r = idx >> 5;
      As[k][r] = A[(size_t)(i0 + r) * 256 + k0 + k];
    }
#pragma unroll
    for (int q = 0; q < 8; ++q) {
      int idx = t + q * 256;
      int c = idx & 63, kk = idx >> 6;
      Ws[kk][c] = W[(size_t)(k0 + kk) * 512 + c0 + c];
    }
    __syncthreads();
#pragma unroll
    for (int kk = 0; kk < 32; ++kk) {
      float4 a = *(const float4*)&As[kk][ty * 4];
      float4 bv = *(const float4*)&Ws[kk][tx * 4];
      float av[4] = {a.x, a.y, a.z, a.w};
      float bb[4] = {bv.x, bv.y, bv.z, bv.w};
#pragma unroll
      for (int m = 0; m < 4; ++m)
#pragma unroll
        for (int n = 0; n < 4; ++n) acc[m][n] += av[m] * bb[n];
    }
  }
  float4 al = *(const float4*)&aw[h * 128 + tx * 4];
  float4 ar = *(const float4*)&aw[h * 128 + 64 + tx * 4];
#pragma unroll
  for (int m = 0; m < 4; ++m) {
    float pl = acc[m][0] * al.x + acc[m][1] * al.y + acc[m][2] * al.z + acc[m][3] * al.w;
    float pr = acc[m][0] * ar.x + acc[m][1] * ar.y + acc[m][2] * ar.z + acc[m][3] * ar.w;
#pragma unroll
    for (int s = 1; s < 16; s <<= 1) {
      pl += __shfl_xor(pl, s);
      pr += __shfl_xor(pr, s);
    }
    if (tx == 0) {
      el[bh * 2048 + n0 + ty * 4 + m] = pl;
      er[bh * 2048 + n0 + ty * 4 + m] = pr;
    }
  }
#pragma unroll
  for (int n = 0; n < 4; ++n) {
    ushort4 us;
    us.x = __half_as_ushort(__float2half(acc[0][n]));
    us.y = __half_as_ushort(__float2half(acc[1][n]));
    us.z = __half_as_ushort(__float2half(acc[2][n]));
    us.w = __half_as_ushort(__float2half(acc[3][n]));
    *(ushort4*)&ct[tx * 4 + n][ty * 4] = us;
  }
  __syncthreads();
  // fragment-order global write: thread t -> fragment f = t>>5, s = t&31 covers lanes s, s+32
  {
    const int f = t >> 5, s = t & 31;
    const int g = f >> 2, nt = f & 3;
    const int r = nt * 16 + (s & 15);
    const int cl = g * 32 + (s >> 4) * 8;
    int4 v0 = *(const int4*)&ct[r][cl];
    int4 v1 = *(const int4*)&ct[r][cl + 16];
    const size_t base = ((size_t)bh * 32 + (n0 >> 6)) * 4096 + f * 512;
    *(int4*)&mt[base + s * 8] = v0;
    *(int4*)&mt[base + (s + 32) * 8] = v1;
  }
}

// ---------------- K2: er_max per (b,h) -------------------------------------
__global__ __launch_bounds__(256) void ermax_kernel(const float* __restrict__ er,
                                                    float* __restrict__ er_max) {
  int bh = blockIdx.x;
  int t = threadIdx.x;
  float m = -1e30f;
  for (int idx = t; idx < 2048; idx += 256) m = fmaxf(m, er[bh * 2048 + idx]);
  __shared__ float red[256];
  red[t] = m;
  __syncthreads();
  for (int s = 128; s > 0; s >>= 1) {
    if (t < s) red[t] = fmaxf(red[t], red[t + s]);
    __syncthreads();
  }
  if (t == 0) er_max[bh] = red[0];
}

// ---------------- K3: fused masked softmax + PV via MFMA -------------------
// 2-way j-split, double-buffered fragment LDS, one barrier per tile.
__global__ __launch_bounds__(512, 8) void gat_attn(const ushort* __restrict__ mt,
                                                   const uint* __restrict__ epk,
                                                   const float* __restrict__ el,
                                                   const float* __restrict__ er,
                                                   const float* __restrict__ ermax,
                                                   float* __restrict__ out) {
  __shared__ __align__(16) char smem[40960];  // vt: 2 buf x 2 half x 8KB = 32KB; er_s 8KB
  int4* vt4 = (int4*)smem;
  float* er_s = (float*)(smem + 32768);
  const int t = threadIdx.x;
  const int l = t & 63;
  const int half = t >> 8;
  const int th = t & 255;
  const int wq = (t >> 6) & 3;
  const int r16 = l & 15, hi = l >> 4;
  const int sh8 = hi * 8;
  const int i0 = blockIdx.x * 64;
  const int h = blockIdx.y, b = blockIdx.z;
  const int bh = b * 8 + h;
  *(float4*)&er_s[t * 4] = *(const float4*)&er[(size_t)bh * 2048 + t * 4];
  const int irow = i0 + wq * 16 + r16;
  const float el_r = el[(size_t)bh * 2048 + irow];
  const float emx = ermax[bh];
  const float s0 = el_r + emx;
  const float m_r = fmaxf(s0, NEG * s0);
  const float m2 = m_r * LOG2E;
  const uint* erow = epk + (size_t)(b * 2048 + irow) * 64;
  f32x4 acc[4];
  f32x4 accL = {0.f, 0.f, 0.f, 0.f};
#pragma unroll
  for (int nt = 0; nt < 4; ++nt) acc[nt] = (f32x4){0.f, 0.f, 0.f, 0.f};
  half8 ones;
#pragma unroll
  for (int c = 0; c < 8; ++c) ones[c] = (_Float16)1.f;

  const int jtg0 = half * 16;
  const int4* srcbase = (const int4*)mt + ((size_t)bh * 32 + jtg0) * 512 + wq * 128 + l;
  int4* mydst0 = vt4 + half * 512 + wq * 128 + l;          // buf 0 slot
  // prologue: stage tile 0 into buf 0
  {
    int4 a0 = srcbase[0];
    int4 a1 = srcbase[64];
    mydst0[0] = a0;
    mydst0[64] = a1;
  }
  __syncthreads();
  int cur = 0;
  for (int jt = 0; jt < 16; ++jt) {
    // issue next tile's loads early (latency hides under score VALU)
    int4 r0, r1;
    if (jt < 15) {
      const int4* s = srcbase + (size_t)(jt + 1) * 512;
      r0 = s[0];
      r1 = s[64];
    }
    const int jtg = jtg0 + jt;
    const unsigned long long wpair = *(const unsigned long long*)(erow + jtg * 2);
    const uint wsh0 = ((uint)wpair) >> sh8;
    const uint wsh1 = ((uint)(wpair >> 32)) >> sh8;
    const int j0 = jtg * 64;
    half8 af[2];
#pragma unroll
    for (int g = 0; g < 2; ++g) {
      float4 u0 = *(const float4*)&er_s[j0 + g * 32 + sh8];
      float4 u1 = *(const float4*)&er_s[j0 + g * 32 + sh8 + 4];
      float uv[8] = {u0.x, u0.y, u0.z, u0.w, u1.x, u1.y, u1.z, u1.w};
      const uint wg = g ? wsh1 : wsh0;
      float pv[8];
#pragma unroll
      for (int c = 0; c < 8; ++c) {
        float s = el_r + uv[c];
        s = fmaxf(s, NEG * s);                     // leaky_relu
        float tt = __builtin_fmaf(s, LOG2E, -m2);  // <= 0
        float p = EXP2F(tt);
        pv[c] = (wg & (1u << c)) ? p : 0.f;
      }
      union {
        half2v h2[4];
        half8 v8;
      } fr;
#pragma unroll
      for (int c = 0; c < 4; ++c) fr.h2[c] = pack2(pv[2 * c], pv[2 * c + 1]);
      af[g] = fr.v8;
    }
    // fragment reads (lane-linear, conflict-free) + MFMA
    const half8* fb = (const half8*)(vt4 + cur * 1024 + half * 512);
#pragma unroll
    for (int g = 0; g < 2; ++g) {
      accL = __builtin_amdgcn_mfma_f32_16x16x32_f16(af[g], ones, accL, 0, 0, 0);
#pragma unroll
      for (int nt = 0; nt < 4; ++nt) {
        half8 bfr = fb[(g * 4 + nt) * 64 + l];
        acc[nt] = __builtin_amdgcn_mfma_f32_16x16x32_f16(af[g], bfr, acc[nt], 0, 0, 0);
      }
    }
    // write staged regs into the alternate buffer
    if (jt < 15) {
      int4* d = vt4 + (cur ^ 1) * 1024 + half * 512 + wq * 128 + l;
      d[0] = r0;
      d[64] = r1;
    }
    __syncthreads();
    cur ^= 1;
  }
  // ---- combine j-halves via LDS (reuses vt region), then epilogue ----
  float* red = (float*)smem;
  if (half == 1) {
    float* dst = red + th * 21;
#pragma unroll
    for (int nt = 0; nt < 4; ++nt)
#pragma unroll
      for (int k = 0; k < 4; ++k) dst[nt * 4 + k] = acc[nt][k];
#pragma unroll
    for (int k = 0; k < 4; ++k) dst[16 + k] = accL[k];
  }
  __syncthreads();
  if (half == 0) {
    const float* src = red + th * 21;
#pragma unroll
    for (int reg = 0; reg < 4; ++reg) {
      float Lrow = accL[reg] + src[16 + reg];
      float invL = 1.f / Lrow;
      int orow = i0 + wq * 16 + hi * 4 + reg;
#pragma unroll
      for (int nt = 0; nt < 4; ++nt) {
        float o = (acc[nt][reg] + src[nt * 4 + reg]) * invL;
        float sig = 1.f / (1.f + __expf(-o));
        out[(size_t)(b * 2048 + orow) * 512 + h * 64 + nt * 16 + r16] = sig;
      }
    }
  }
}

extern "C" void kernel_launch(void* const* d_in, const int* in_sizes, int n_in,
                              void* d_out, int out_size, void* d_ws, size_t ws_size,
                              hipStream_t stream) {
  const float* nodes = (const float*)d_in[0];
  const int* edges = (const int*)d_in[1];
  const float* pw = (const float*)d_in[2];
  const float* aw = (const float*)d_in[3];
  float* out = (float*)d_out;

  ushort* mt = (ushort*)d_ws;                         // 8,388,608 B
  float* el = (float*)((char*)d_ws + 8388608);        // 262,144 B
  float* er = (float*)((char*)d_ws + 8650752);        // 262,144 B
  float* ermax = (float*)((char*)d_ws + 8912896);     // 128 B
  uint* epk = (uint*)((char*)d_ws + 8913024);         // 2,097,152 B

  pack_edges<<<2048, 256, 0, stream>>>(edges, epk);
  proj_fused<<<dim3(128, 8), 256, 0, stream>>>(nodes, pw, aw, mt, el, er);
  ermax_kernel<<<32, 256, 0, stream>>>(er, ermax);
  gat_attn<<<dim3(32, 8, 4), 512, 0, stream>>>(mt, epk, el, er, ermax, out);
}